// Round 5
// baseline (280.944 us; speedup 1.0000x reference)
//
#include <hip/hip_runtime.h>

#define NROWS 4096
#define LV 128
#define H 256
#define D 256
#define K_IN 768   // 3*D
#define LN_EPS 1e-5f
#define BM 8

#define COMPUTE_BLOCKS (NROWS / BM)   // 512
#define COPY_BLOCKS    2048           // 4 waves each; wave = half an n-slab (64 rows)

typedef __attribute__((ext_vector_type(4))) float f4;

__global__ __launch_bounds__(256) void coord_fused(
    const float* __restrict__ memory,
    const int*   __restrict__ veh_idx,
    const float* __restrict__ veh_repr,
    const float* __restrict__ cust_repr,
    const float* __restrict__ edge_emb,
    const float* __restrict__ W_in,
    const float* __restrict__ b_in,
    const float* __restrict__ W_h,
    const float* __restrict__ b_h,
    const float* __restrict__ gamma,
    const float* __restrict__ beta,
    float* __restrict__ out)
{
    __shared__ float xs[BM * 1024];
    __shared__ int   idxs[BM];

    const int tid = threadIdx.x;

    if (blockIdx.x >= COMPUTE_BLOCKS) {
        // ---------------- copy path: all (n, l != idx[n]) rows (R2 structure) ----------------
        const int cb   = blockIdx.x - COMPUTE_BLOCKS;
        const int wid  = tid >> 6;
        const int lane = tid & 63;
        const int w    = cb * 4 + wid;      // 0..8191
        const int n    = w >> 1;            // 0..4095
        const int l0   = (w & 1) * 64;      // half-slab
        const int idxn = veh_idx[n];

        const size_t base = ((size_t)n * LV + l0) * H + (size_t)lane * 4;
        const float4* src = (const float4*)(memory + base);
        float4*       dst = (float4*)(out + base);

        for (int l = 0; l < 64; l += 4) {
            float4 v0 = src[(size_t)(l + 0) * 64];
            float4 v1 = src[(size_t)(l + 1) * 64];
            float4 v2 = src[(size_t)(l + 2) * 64];
            float4 v3 = src[(size_t)(l + 3) * 64];
            if (l0 + l + 0 != idxn) dst[(size_t)(l + 0) * 64] = v0;
            if (l0 + l + 1 != idxn) dst[(size_t)(l + 1) * 64] = v1;
            if (l0 + l + 2 != idxn) dst[(size_t)(l + 2) * 64] = v2;
            if (l0 + l + 3 != idxn) dst[(size_t)(l + 3) * 64] = v3;
        }
        return;
    }

    // ---------------- compute path: the (n, idx[n]) rows ----------------
    // Wave w owns rows {2w, 2w+1}; lane l owns cols {4l..4l+3}.
    const int row0 = blockIdx.x * BM;
    const int wid  = tid >> 6;
    const int lane = tid & 63;

    if (tid < BM) idxs[tid] = veh_idx[row0 + tid];

    const float4* v4 = (const float4*)(veh_repr + (size_t)row0 * D);
    const float4* c4 = (const float4*)(cust_repr + (size_t)row0 * D);
    const float4* e4 = (const float4*)(edge_emb + (size_t)row0 * D);
    for (int i = tid; i < BM * 64; i += 256) {
        int m = i >> 6, c = (i & 63) << 2;
        *(float4*)&xs[m * 1024 + 0   + c] = v4[i];
        *(float4*)&xs[m * 1024 + 256 + c] = c4[i];
        *(float4*)&xs[m * 1024 + 512 + c] = e4[i];
    }
    __syncthreads();  // idxs visible
    for (int i = tid; i < BM * 64; i += 256) {
        int m = i >> 6, c = (i & 63) << 2;
        const float4* src =
            (const float4*)(memory + (size_t)(row0 + m) * LV * H + (size_t)idxs[m] * H);
        *(float4*)&xs[m * 1024 + 768 + c] = src[i & 63];
    }
    __syncthreads();

    const int m0 = wid * 2;           // this wave's first row
    const int c0 = lane * 4;          // this lane's first col

    f4 acc0 = {0.f, 0.f, 0.f, 0.f};
    f4 acc1 = {0.f, 0.f, 0.f, 0.f};

    // x[:, 0:768] @ W_in[:, c0..c0+3]
    for (int k = 0; k < K_IN; k += 4) {
        f4 w0 = *(const f4*)&W_in[(size_t)(k + 0) * H + c0];
        f4 w1 = *(const f4*)&W_in[(size_t)(k + 1) * H + c0];
        f4 w2 = *(const f4*)&W_in[(size_t)(k + 2) * H + c0];
        f4 w3 = *(const f4*)&W_in[(size_t)(k + 3) * H + c0];
        f4 x0 = *(const f4*)&xs[(m0 + 0) * 1024 + k];   // wave-broadcast
        f4 x1 = *(const f4*)&xs[(m0 + 1) * 1024 + k];   // wave-broadcast
        acc0 += x0.x * w0 + x0.y * w1 + x0.z * w2 + x0.w * w3;
        acc1 += x1.x * w0 + x1.y * w1 + x1.z * w2 + x1.w * w3;
    }
    // cur_h @ W_h[:, c0..c0+3]
    for (int k = 0; k < H; k += 4) {
        f4 w0 = *(const f4*)&W_h[(size_t)(k + 0) * H + c0];
        f4 w1 = *(const f4*)&W_h[(size_t)(k + 1) * H + c0];
        f4 w2 = *(const f4*)&W_h[(size_t)(k + 2) * H + c0];
        f4 w3 = *(const f4*)&W_h[(size_t)(k + 3) * H + c0];
        f4 x0 = *(const f4*)&xs[(m0 + 0) * 1024 + 768 + k];
        f4 x1 = *(const f4*)&xs[(m0 + 1) * 1024 + 768 + k];
        acc0 += x0.x * w0 + x0.y * w1 + x0.z * w2 + x0.w * w3;
        acc1 += x1.x * w0 + x1.y * w1 + x1.z * w2 + x1.w * w3;
    }

    const f4 bsum = *(const f4*)&b_in[c0] + *(const f4*)&b_h[c0];
    acc0 += bsum;
    acc1 += bsum;

    // Per-row LayerNorm: row fully within this wave -> 64-lane butterfly.
    float s0 = acc0.x + acc0.y + acc0.z + acc0.w;
    float s1 = acc1.x + acc1.y + acc1.z + acc1.w;
    float q0 = acc0.x * acc0.x + acc0.y * acc0.y + acc0.z * acc0.z + acc0.w * acc0.w;
    float q1 = acc1.x * acc1.x + acc1.y * acc1.y + acc1.z * acc1.z + acc1.w * acc1.w;
#pragma unroll
    for (int off = 32; off; off >>= 1) {
        s0 += __shfl_xor(s0, off);
        s1 += __shfl_xor(s1, off);
        q0 += __shfl_xor(q0, off);
        q1 += __shfl_xor(q1, off);
    }
    const float mu0 = s0 * (1.f / H), mu1 = s1 * (1.f / H);
    const float r0  = rsqrtf(q0 * (1.f / H) - mu0 * mu0 + LN_EPS);
    const float r1  = rsqrtf(q1 * (1.f / H) - mu1 * mu1 + LN_EPS);

    const f4 g = *(const f4*)&gamma[c0];
    const f4 b = *(const f4*)&beta[c0];

    f4 o0, o1;
    o0.x = tanhf((acc0.x - mu0) * r0 * g.x + b.x);
    o0.y = tanhf((acc0.y - mu0) * r0 * g.y + b.y);
    o0.z = tanhf((acc0.z - mu0) * r0 * g.z + b.z);
    o0.w = tanhf((acc0.w - mu0) * r0 * g.w + b.w);
    o1.x = tanhf((acc1.x - mu1) * r1 * g.x + b.x);
    o1.y = tanhf((acc1.y - mu1) * r1 * g.y + b.y);
    o1.z = tanhf((acc1.z - mu1) * r1 * g.z + b.z);
    o1.w = tanhf((acc1.w - mu1) * r1 * g.w + b.w);

    *(f4*)&out[(size_t)(row0 + m0 + 0) * LV * H + (size_t)idxs[m0 + 0] * H + c0] = o0;
    *(f4*)&out[(size_t)(row0 + m0 + 1) * LV * H + (size_t)idxs[m0 + 1] * H + c0] = o1;
}

extern "C" void kernel_launch(void* const* d_in, const int* in_sizes, int n_in,
                              void* d_out, int out_size, void* d_ws, size_t ws_size,
                              hipStream_t stream) {
    const float* memory    = (const float*)d_in[0];
    const int*   veh_idx   = (const int*)d_in[1];
    const float* veh_repr  = (const float*)d_in[2];
    const float* cust_repr = (const float*)d_in[3];
    const float* edge_emb  = (const float*)d_in[4];
    const float* W_in      = (const float*)d_in[5];
    const float* b_in      = (const float*)d_in[6];
    const float* W_h       = (const float*)d_in[7];
    const float* b_h       = (const float*)d_in[8];
    const float* gamma     = (const float*)d_in[9];
    const float* beta      = (const float*)d_in[10];
    float* out = (float*)d_out;

    coord_fused<<<COMPUTE_BLOCKS + COPY_BLOCKS, 256, 0, stream>>>(
        memory, veh_idx, veh_repr, cust_repr, edge_emb,
        W_in, b_in, W_h, b_h, gamma, beta, out);
}

// Round 6
// 220.732 us; speedup vs baseline: 1.2728x; 1.2728x over previous
//
#include <hip/hip_runtime.h>

#define NROWS 4096
#define LV 128
#define H 256
#define D 256
#define LN_EPS 1e-5f

#define CBLK 64            // compute blocks: 64 rows each (4 waves x 16 rows)
#define COPY_BLOCKS 2048   // R2 copy structure

typedef __attribute__((ext_vector_type(4))) float  f32x4;
typedef __attribute__((ext_vector_type(8))) short  bf16x8;

__device__ __forceinline__ short f2bf(float f) {
    union { float f; unsigned u; } a; a.f = f;
    unsigned r = a.u + 0x7FFFu + ((a.u >> 16) & 1u);
    return (short)(r >> 16);
}

// ---- kernel 1: W_in||W_h (1024x256 f32) -> MFMA B-fragment-ordered bf16 in ws ----
// frag fid = nt*32 + t : 64 lanes x 8 bf16.  lane l holds B[k=t*32+(l>>4)*8+e][col=nt*16+(l&15)]
__global__ __launch_bounds__(256) void wconv(
    const float* __restrict__ W_in, const float* __restrict__ W_h,
    short* __restrict__ wsb)
{
    const int fid = blockIdx.x * 4 + (threadIdx.x >> 6);  // 0..511
    const int l   = threadIdx.x & 63;
    const int nt  = fid >> 5, t = fid & 31;
    const int col = nt * 16 + (l & 15);
    const int k0  = t * 32 + (l >> 4) * 8;
    bf16x8 o;
#pragma unroll
    for (int e = 0; e < 8; e++) {
        int k = k0 + e;
        float x = (k < 768) ? W_in[(size_t)k * H + col] : W_h[(size_t)(k - 768) * H + col];
        o[e] = f2bf(x);
    }
    *(bf16x8*)&wsb[(size_t)fid * 512 + l * 8] = o;
}

__global__ __launch_bounds__(256) void coord_fused(
    const float* __restrict__ memory,
    const int*   __restrict__ veh_idx,
    const float* __restrict__ veh_repr,
    const float* __restrict__ cust_repr,
    const float* __restrict__ edge_emb,
    const float* __restrict__ b_in,
    const float* __restrict__ b_h,
    const float* __restrict__ gamma,
    const float* __restrict__ beta,
    const short* __restrict__ wsb,
    float* __restrict__ out)
{
    const int tid = threadIdx.x;

    if (blockIdx.x >= CBLK) {
        // ---------------- copy path (R2 verbatim): all (n, l != idx[n]) rows ----------------
        const int cb   = blockIdx.x - CBLK;
        const int wid  = tid >> 6;
        const int lane = tid & 63;
        const int w    = cb * 4 + wid;      // 0..8191
        const int n    = w >> 1;            // 0..4095
        const int l0   = (w & 1) * 64;      // half-slab
        const int idxn = veh_idx[n];

        const size_t base = ((size_t)n * LV + l0) * H + (size_t)lane * 4;
        const float4* src = (const float4*)(memory + base);
        float4*       dst = (float4*)(out + base);

        for (int l = 0; l < 64; l += 4) {
            float4 v0 = src[(size_t)(l + 0) * 64];
            float4 v1 = src[(size_t)(l + 1) * 64];
            float4 v2 = src[(size_t)(l + 2) * 64];
            float4 v3 = src[(size_t)(l + 3) * 64];
            if (l0 + l + 0 != idxn) dst[(size_t)(l + 0) * 64] = v0;
            if (l0 + l + 1 != idxn) dst[(size_t)(l + 1) * 64] = v1;
            if (l0 + l + 2 != idxn) dst[(size_t)(l + 2) * 64] = v2;
            if (l0 + l + 3 != idxn) dst[(size_t)(l + 3) * 64] = v3;
        }
        return;
    }

    // ---------------- compute path: MFMA, wave = 16 rows x 256 cols ----------------
    const int w     = tid >> 6;
    const int l     = tid & 63;
    const int row0w = blockIdx.x * 64 + w * 16;   // this wave's first row

    // A-operand: lane l holds A[row=l&15][k=(l>>4)*8 + e] per k-step
    const int arow = row0w + (l & 15);
    const int kg8  = (l >> 4) * 8;
    const int idxA = veh_idx[arow];

    const float* pV = veh_repr  + (size_t)arow * D + kg8;
    const float* pC = cust_repr + (size_t)arow * D + kg8;
    const float* pE = edge_emb  + (size_t)arow * D + kg8;
    const float* pM = memory + (size_t)arow * LV * H + (size_t)idxA * H + kg8;

    f32x4 acc[16];
#pragma unroll
    for (int nt = 0; nt < 16; nt++) acc[nt] = (f32x4){0.f, 0.f, 0.f, 0.f};

#define DO_SEG(BASE, T0)                                                        \
    _Pragma("unroll")                                                           \
    for (int tt = 0; tt < 8; tt++) {                                            \
        const int t = (T0) + tt;                                                \
        f32x4 xa = *(const f32x4*)((BASE) + tt * 32);                           \
        f32x4 xb = *(const f32x4*)((BASE) + tt * 32 + 4);                       \
        bf16x8 afrag;                                                           \
        afrag[0] = f2bf(xa[0]); afrag[1] = f2bf(xa[1]);                         \
        afrag[2] = f2bf(xa[2]); afrag[3] = f2bf(xa[3]);                         \
        afrag[4] = f2bf(xb[0]); afrag[5] = f2bf(xb[1]);                         \
        afrag[6] = f2bf(xb[2]); afrag[7] = f2bf(xb[3]);                         \
        _Pragma("unroll")                                                       \
        for (int nt = 0; nt < 16; nt++) {                                       \
            bf16x8 bfrag = *(const bf16x8*)&wsb[(size_t)(nt * 32 + t) * 512 + l * 8]; \
            acc[nt] = __builtin_amdgcn_mfma_f32_16x16x32_bf16(afrag, bfrag, acc[nt], 0, 0, 0); \
        }                                                                       \
    }

    DO_SEG(pV, 0)
    DO_SEG(pC, 8)
    DO_SEG(pE, 16)
    DO_SEG(pM, 24)
#undef DO_SEG

    // C/D layout (m89-verified): col = nt*16 + (l&15), row = (l>>4)*4 + i
    const int c_lo = l & 15;

    // bias add (per column)
#pragma unroll
    for (int nt = 0; nt < 16; nt++) {
        float bsum = b_in[nt * 16 + c_lo] + b_h[nt * 16 + c_lo];
#pragma unroll
        for (int i = 0; i < 4; i++) acc[nt][i] += bsum;
    }

    // LayerNorm per row: reduce over 16 nt (in-lane) then 16 lanes (butterfly)
    float s[4] = {0.f, 0.f, 0.f, 0.f}, q[4] = {0.f, 0.f, 0.f, 0.f};
#pragma unroll
    for (int nt = 0; nt < 16; nt++)
#pragma unroll
        for (int i = 0; i < 4; i++) {
            float v = acc[nt][i];
            s[i] += v; q[i] += v * v;
        }
#pragma unroll
    for (int off = 1; off < 16; off <<= 1)
#pragma unroll
        for (int i = 0; i < 4; i++) {
            s[i] += __shfl_xor(s[i], off);
            q[i] += __shfl_xor(q[i], off);
        }

    float mu[4], rs[4];
#pragma unroll
    for (int i = 0; i < 4; i++) {
        mu[i] = s[i] * (1.f / H);
        rs[i] = rsqrtf(q[i] * (1.f / H) - mu[i] * mu[i] + LN_EPS);
    }

#pragma unroll
    for (int i = 0; i < 4; i++) {
        const int grow = row0w + (l >> 4) * 4 + i;
        const int idxC = veh_idx[grow];
        float* po = out + (size_t)grow * LV * H + (size_t)idxC * H + c_lo;
#pragma unroll
        for (int nt = 0; nt < 16; nt++) {
            float g  = gamma[nt * 16 + c_lo];
            float be = beta[nt * 16 + c_lo];
            float ln = (acc[nt][i] - mu[i]) * rs[i] * g + be;
            po[nt * 16] = tanhf(ln);
        }
    }
}

extern "C" void kernel_launch(void* const* d_in, const int* in_sizes, int n_in,
                              void* d_out, int out_size, void* d_ws, size_t ws_size,
                              hipStream_t stream) {
    const float* memory    = (const float*)d_in[0];
    const int*   veh_idx   = (const int*)d_in[1];
    const float* veh_repr  = (const float*)d_in[2];
    const float* cust_repr = (const float*)d_in[3];
    const float* edge_emb  = (const float*)d_in[4];
    const float* W_in      = (const float*)d_in[5];
    const float* b_in      = (const float*)d_in[6];
    const float* W_h       = (const float*)d_in[7];
    const float* b_h       = (const float*)d_in[8];
    const float* gamma     = (const float*)d_in[9];
    const float* beta      = (const float*)d_in[10];
    float* out = (float*)d_out;
    short* wsb = (short*)d_ws;   // 512 KB of B-fragments

    wconv<<<128, 256, 0, stream>>>(W_in, W_h, wsb);
    coord_fused<<<CBLK + COPY_BLOCKS, 256, 0, stream>>>(
        memory, veh_idx, veh_repr, cust_repr, edge_emb,
        b_in, b_h, gamma, beta, wsb, out);
}